// Round 5
// baseline (1096.606 us; speedup 1.0000x reference)
//
#include <hip/hip_runtime.h>

#define S_VOX (128*128*128)   // voxels per (b,n) plane
#define QV (S_VOX/4)          // float4 groups per plane = 524288
#define EPSF 1e-10f
#define SMOOTHF 1e-5f
#define LN2F 0.6931471805599453f

// ws float slots: [plane]=ce(log2), [16+plane]=inter, [32+plane]=ground,
//                 [48+plane]=pred_o, [64]=done counter. packed[] at ws+128.
#define NSLOT 64
#define TILES_PER_PLANE 512   // QV / 1024
#define NBLK (16 * TILES_PER_PLANE)   // 8192

// ------------------------------------------------------------------
// Kernel A: pack both batches' 3-bit targets per voxel-quad into one u32.
// bits [6c..6c+2]=t0.c, [6c+3..6c+5]=t1.c. Block 0 also zeroes ws slots.
// ------------------------------------------------------------------
__global__ __launch_bounds__(256) void pack_targets(const int* __restrict__ tgt,
                                                    unsigned int* __restrict__ packed,
                                                    float* __restrict__ ws) {
    if (blockIdx.x == 0 && threadIdx.x <= NSLOT) ws[threadIdx.x] = 0.f;
    const int4* t4 = (const int4*)tgt;
    int q = blockIdx.x * 1024 + threadIdx.x;
#pragma unroll
    for (int i = 0; i < 4; i++, q += 256) {
        const int4 t0 = t4[q];
        const int4 t1 = t4[QV + q];
        unsigned int m = (unsigned)(t0.x & 7)        | ((unsigned)(t1.x & 7) << 3)
                       | ((unsigned)(t0.y & 7) << 6) | ((unsigned)(t1.y & 7) << 9)
                       | ((unsigned)(t0.z & 7) << 12)| ((unsigned)(t1.z & 7) << 15)
                       | ((unsigned)(t0.w & 7) << 18)| ((unsigned)(t1.w & 7) << 21);
        packed[q] = m;
    }
}

// ------------------------------------------------------------------
// Kernel B: straight-line, one 16KB tile of one plane per block.
// Exactly ONE memory round trip per thread: 4 float4 + 4 u32, no loops.
// ------------------------------------------------------------------
__global__ __launch_bounds__(256) void dice_main(const float* __restrict__ pred,
                                                 const unsigned int* __restrict__ packed,
                                                 float* __restrict__ ws,
                                                 float* __restrict__ out) {
    const int plane = blockIdx.x >> 9;        // [0,16): b = plane>>3, n = plane&7
    const int tile  = blockIdx.x & 511;
    const int b     = plane >> 3;
    const int n     = plane & 7;
    const int t     = threadIdx.x;

    const float4* p4 = (const float4*)pred + (size_t)plane * QV + tile * 1024;
    const unsigned int* pk = packed + tile * 1024;

    // ---- all 8 loads issued up front, fully independent ----
    const float4 v0 = p4[t];
    const float4 v1 = p4[256 + t];
    const float4 v2 = p4[512 + t];
    const float4 v3 = p4[768 + t];
    const unsigned m0 = pk[t];
    const unsigned m1 = pk[256 + t];
    const unsigned m2 = pk[512 + t];
    const unsigned m3 = pk[768 + t];

    float ce = 0.f, inter = 0.f, gnd = 0.f, po = 0.f;

#define COMP(pv, m, sh)                                                  \
    {                                                                    \
        const int c0 = (int)(((m) >> (sh))     & 7u) == n;               \
        const int c1 = (int)(((m) >> ((sh)+3)) & 7u) == n;               \
        const float lg = __log2f((pv) + EPSF);                           \
        ce += (float)(c0 + c1) * lg;                                     \
        const int mb = b ? c1 : c0;                                      \
        inter += mb ? (pv) : 0.f;                                        \
        gnd   += (float)mb;                                              \
        po    += (pv);                                                   \
    }
#define GROUP(v, m) COMP(v.x, m, 0) COMP(v.y, m, 6) COMP(v.z, m, 12) COMP(v.w, m, 18)
    GROUP(v0, m0) GROUP(v1, m1) GROUP(v2, m2) GROUP(v3, m3)
#undef GROUP
#undef COMP

    // ---- block reduction: 64-lane shuffle -> LDS -> 4 atomics ----
    __shared__ float red[4][4];
    const int lane = t & 63;
    const int wave = t >> 6;
    float v4[4] = {ce, inter, gnd, po};
#pragma unroll
    for (int i = 0; i < 4; i++) {
#pragma unroll
        for (int off = 32; off > 0; off >>= 1)
            v4[i] += __shfl_down(v4[i], off, 64);
        if (lane == 0) red[wave][i] = v4[i];
    }
    __syncthreads();
    if (t < 4) {
        const float s = red[0][t] + red[1][t] + red[2][t] + red[3][t];
        atomicAdd(&ws[t * 16 + plane], s);
    }

    // ---- last-block finalize ----
    __threadfence();
    __syncthreads();
    if (t == 0) {
        const unsigned prev = atomicAdd((unsigned int*)(ws + NSLOT), 1u);
        if (prev == (unsigned)(gridDim.x - 1)) {
            float acc[NSLOT];
#pragma unroll
            for (int i = 0; i < NSLOT; i++) acc[i] = atomicAdd(&ws[i], 0.0f); // coherent read
            float ce_tot = 0.f, dice = 0.f;
#pragma unroll
            for (int k = 0; k < 16; k++) {
                ce_tot += acc[k];
                dice += 1.0f - (2.0f * acc[16 + k] + SMOOTHF)
                              / (acc[32 + k] + acc[48 + k] + SMOOTHF);
            }
            out[0] = -(ce_tot * LN2F) / (4.0f * (float)S_VOX) + dice * (1.0f / 16.0f);
        }
    }
}

extern "C" void kernel_launch(void* const* d_in, const int* in_sizes, int n_in,
                              void* d_out, int out_size, void* d_ws, size_t ws_size,
                              hipStream_t stream) {
    const float* pred = (const float*)d_in[0];
    const int*   tgt  = (const int*)d_in[1];
    float*        ws     = (float*)d_ws;                 // slots + counter
    unsigned int* packed = (unsigned int*)(ws + 128);    // QV u32 = 2 MB scratch
    float* out = (float*)d_out;

    pack_targets<<<QV / 1024, 256, 0, stream>>>(tgt, packed, ws);
    dice_main<<<NBLK, 256, 0, stream>>>(pred, packed, ws, out);
}

// Round 6
// 1095.458 us; speedup vs baseline: 1.0010x; 1.0010x over previous
//
#include <hip/hip_runtime.h>

#define S_VOX (128*128*128)   // voxels per (b,n) plane
#define QV (S_VOX/4)          // float4 groups per plane = 524288
#define EPSF 1e-10f
#define SMOOTHF 1e-5f
#define LN2F 0.6931471805599453f

// ws float slots: [plane]=ce(log2), [16+plane]=inter, [32+plane]=ground,
//                 [48+plane]=pred_o, [64]=done counter. packed[] at ws+128.
#define NSLOT 64
#define TILES_PER_PLANE 512   // QV / 1024
#define NBLK (16 * TILES_PER_PLANE)   // 8192

// ------------------------------------------------------------------
// Kernel A: pack both batches' 3-bit targets per voxel-quad into one u32.
// bits [6c..6c+2]=t0.c, [6c+3..6c+5]=t1.c. Block 0 also zeroes ws slots.
// ------------------------------------------------------------------
__global__ __launch_bounds__(256) void pack_targets(const int* __restrict__ tgt,
                                                    unsigned int* __restrict__ packed,
                                                    float* __restrict__ ws) {
    if (blockIdx.x == 0 && threadIdx.x <= NSLOT) ws[threadIdx.x] = 0.f;
    const int4* t4 = (const int4*)tgt;
    int q = blockIdx.x * 1024 + threadIdx.x;
#pragma unroll
    for (int i = 0; i < 4; i++, q += 256) {
        const int4 t0 = t4[q];
        const int4 t1 = t4[QV + q];
        unsigned int m = (unsigned)(t0.x & 7)        | ((unsigned)(t1.x & 7) << 3)
                       | ((unsigned)(t0.y & 7) << 6) | ((unsigned)(t1.y & 7) << 9)
                       | ((unsigned)(t0.z & 7) << 12)| ((unsigned)(t1.z & 7) << 15)
                       | ((unsigned)(t0.w & 7) << 18)| ((unsigned)(t1.w & 7) << 21);
        packed[q] = m;
    }
}

// ------------------------------------------------------------------
// Kernel B: straight-line, one 16KB tile of one plane per block.
// ONE memory round trip per thread: 4 float4 + 4 u32, no loops.
// waves_per_eu(4,8): VGPR budget 128 (min) — forbids the allocator's
// 16-wave/32-VGPR spill target that destroyed R5 (WRITE_SIZE 1.28 GB).
// ------------------------------------------------------------------
__global__ __launch_bounds__(256)
__attribute__((amdgpu_waves_per_eu(4, 8)))
void dice_main(const float* __restrict__ pred,
               const unsigned int* __restrict__ packed,
               float* __restrict__ ws,
               float* __restrict__ out) {
    const int plane = blockIdx.x >> 9;        // [0,16): b = plane>>3, n = plane&7
    const int tile  = blockIdx.x & 511;
    const int b     = plane >> 3;
    const int n     = plane & 7;
    const int t     = threadIdx.x;

    const float4* p4 = (const float4*)pred + (size_t)plane * QV + tile * 1024;
    const unsigned int* pk = packed + tile * 1024;

    // ---- all 8 loads issued up front, fully independent ----
    const float4 v0 = p4[t];
    const float4 v1 = p4[256 + t];
    const float4 v2 = p4[512 + t];
    const float4 v3 = p4[768 + t];
    const unsigned m0 = pk[t];
    const unsigned m1 = pk[256 + t];
    const unsigned m2 = pk[512 + t];
    const unsigned m3 = pk[768 + t];

    float ce = 0.f, inter = 0.f, gnd = 0.f, po = 0.f;

#define COMP(pv, m, sh)                                                  \
    {                                                                    \
        const int c0 = (int)(((m) >> (sh))     & 7u) == n;               \
        const int c1 = (int)(((m) >> ((sh)+3)) & 7u) == n;               \
        const float lg = __log2f((pv) + EPSF);                           \
        ce += (float)(c0 + c1) * lg;                                     \
        const int mb = b ? c1 : c0;                                      \
        inter += mb ? (pv) : 0.f;                                        \
        gnd   += (float)mb;                                              \
        po    += (pv);                                                   \
    }
#define GROUP(v, m) COMP(v.x, m, 0) COMP(v.y, m, 6) COMP(v.z, m, 12) COMP(v.w, m, 18)
    GROUP(v0, m0) GROUP(v1, m1) GROUP(v2, m2) GROUP(v3, m3)
#undef GROUP
#undef COMP

    // ---- block reduction: 64-lane shuffle -> LDS -> 4 atomics ----
    __shared__ float red[4][4];
    const int lane = t & 63;
    const int wave = t >> 6;
    float v4[4] = {ce, inter, gnd, po};
#pragma unroll
    for (int i = 0; i < 4; i++) {
#pragma unroll
        for (int off = 32; off > 0; off >>= 1)
            v4[i] += __shfl_down(v4[i], off, 64);
        if (lane == 0) red[wave][i] = v4[i];
    }
    __syncthreads();
    if (t < 4) {
        const float s = red[0][t] + red[1][t] + red[2][t] + red[3][t];
        atomicAdd(&ws[t * 16 + plane], s);
    }

    // ---- last-block finalize ----
    __threadfence();
    __syncthreads();
    if (t == 0) {
        const unsigned prev = atomicAdd((unsigned int*)(ws + NSLOT), 1u);
        if (prev == (unsigned)(gridDim.x - 1)) {
            float acc[NSLOT];
#pragma unroll
            for (int i = 0; i < NSLOT; i++) acc[i] = atomicAdd(&ws[i], 0.0f); // coherent read
            float ce_tot = 0.f, dice = 0.f;
#pragma unroll
            for (int k = 0; k < 16; k++) {
                ce_tot += acc[k];
                dice += 1.0f - (2.0f * acc[16 + k] + SMOOTHF)
                              / (acc[32 + k] + acc[48 + k] + SMOOTHF);
            }
            out[0] = -(ce_tot * LN2F) / (4.0f * (float)S_VOX) + dice * (1.0f / 16.0f);
        }
    }
}

extern "C" void kernel_launch(void* const* d_in, const int* in_sizes, int n_in,
                              void* d_out, int out_size, void* d_ws, size_t ws_size,
                              hipStream_t stream) {
    const float* pred = (const float*)d_in[0];
    const int*   tgt  = (const int*)d_in[1];
    float*        ws     = (float*)d_ws;                 // slots + counter
    unsigned int* packed = (unsigned int*)(ws + 128);    // QV u32 = 2 MB scratch
    float* out = (float*)d_out;

    pack_targets<<<QV / 1024, 256, 0, stream>>>(tgt, packed, ws);
    dice_main<<<NBLK, 256, 0, stream>>>(pred, packed, ws, out);
}